// Round 3
// baseline (22001.163 us; speedup 1.0000x reference)
//
#include <hip/hip_runtime.h>
#include <cstdint>
#include <cstddef>

#define BB 32
#define TT 512
#define NSTEPS 129   // L+1
#define EE 1024
#define DD 1024
#define AAD 512
#define VV 5000
#define SOS 4999
#define KW 201
#define NFILT 100
#define NBLK 256
#define NTHR 512

__device__ __forceinline__ float fsig(float x){
    return __fdividef(1.0f, 1.0f + __expf(-x));
}
__device__ __forceinline__ float ftanh(float x){
    float ax = fabsf(x);
    float e = __expf(-2.0f*ax);
    float r = __fdividef(1.0f - e, 1.0f + e);
    return copysignf(r, x);
}

// 64-lane reduce-scatter butterfly: on entry lane holds cur[0..63] partials;
// on exit lane l holds full sum of component bitrev6(l) in cur[0].
__device__ __forceinline__ void butterfly64(float* cur, int lane){
#pragma unroll
    for (int rb = 0; rb < 6; ++rb){
        const int bit = 1 << rb;
        const int half = 32 >> rb;
        const bool up = (lane & bit) != 0;
#pragma unroll
        for (int i = 0; i < half; ++i){
            float lo = cur[i], hi = cur[i + half];
            float send = up ? lo : hi;
            float keep = up ? hi : lo;
            cur[i] = keep + __shfl_xor(send, bit);
        }
    }
}

// grid barrier: per-block flag stores (padded lines) + master (block 0) polls
// + bumps gen. Device-scope atomics; __threadfence() for cross-XCD visibility.
__device__ __forceinline__ void gbar(int* flags, int* gen, int ep){
    __syncthreads();
    if (threadIdx.x == 0){
        __threadfence();
        __hip_atomic_store(&flags[blockIdx.x*16], ep, __ATOMIC_RELEASE,
                           __HIP_MEMORY_SCOPE_AGENT);
    }
    if (blockIdx.x == 0){
        if (threadIdx.x < NBLK){
            while (__hip_atomic_load(&flags[threadIdx.x*16], __ATOMIC_RELAXED,
                                     __HIP_MEMORY_SCOPE_AGENT) < ep)
                __builtin_amdgcn_s_sleep(2);
        }
        __syncthreads();
        if (threadIdx.x == 0)
            __hip_atomic_store(gen, ep, __ATOMIC_RELEASE,
                               __HIP_MEMORY_SCOPE_AGENT);
    } else {
        if (threadIdx.x == 0){
            while (__hip_atomic_load(gen, __ATOMIC_RELAXED,
                                     __HIP_MEMORY_SCOPE_AGENT) < ep)
                __builtin_amdgcn_s_sleep(2);
        }
    }
    if (threadIdx.x == 0) __threadfence();
    __syncthreads();
}

// ---------------------------------------------------------------------------
__global__ void k_init(const int* __restrict__ hlens, float* __restrict__ aw,
                       float* __restrict__ z0a, float* __restrict__ z1a,
                       float* __restrict__ g1dec, float* __restrict__ c0,
                       float* __restrict__ c1, int* __restrict__ bar)
{
    int idx = blockIdx.x*256 + threadIdx.x;   // 128 blocks -> 32768 threads
    if (idx < BB*TT){
        int b = idx >> 9, t = idx & 511;
        int hl = hlens[b];
        aw[idx] = (t < hl) ? __fdividef(1.0f, (float)hl) : 0.0f;
    }
    if (idx < BB*1024){
        z0a[idx] = 0.0f; z1a[idx] = 0.0f; c0[idx] = 0.0f; c1[idx] = 0.0f;
    }
    if (idx < BB*AAD) g1dec[idx] = 0.0f;
    if (idx < 8192)   bar[idx] = 0;
}

// ---------------------------------------------------------------------------
// generic fp32 NT GEMM (unchanged from verified R2): C[m][n]=sum_k A[m][k]B[n][k]+bias
template<bool GUARD, bool REMAP>
__global__ __launch_bounds__(256) void k_gemm_nt(
    const float* __restrict__ Am, const float* __restrict__ Bm,
    const float* __restrict__ bias, float* __restrict__ Cm,
    int M, int N, int K)
{
    __shared__ float as[16][132];
    __shared__ float bs[16][68];
    const int tid = threadIdx.x;
    const int m0 = blockIdx.x * 128, n0 = blockIdx.y * 64;
    const int tm = tid & 15, tn = tid >> 4;
    float acc[8][4];
#pragma unroll
    for (int i = 0; i < 8; ++i)
#pragma unroll
        for (int j = 0; j < 4; ++j) acc[i][j] = 0.0f;

    for (int k0 = 0; k0 < K; k0 += 16){
#pragma unroll
        for (int i = 0; i < 2; ++i){
            int idx = tid + i*256;
            int r = idx >> 2, q = idx & 3;
            int row = m0 + r;
            float4 v = make_float4(0.f,0.f,0.f,0.f);
            if (!GUARD || row < M) v = *(const float4*)(Am + (size_t)row*K + k0 + q*4);
            as[q*4+0][r] = v.x; as[q*4+1][r] = v.y;
            as[q*4+2][r] = v.z; as[q*4+3][r] = v.w;
        }
        {
            int r = tid >> 2, q = tid & 3;
            int row = n0 + r;
            float4 v = make_float4(0.f,0.f,0.f,0.f);
            if (!GUARD || row < N) v = *(const float4*)(Bm + (size_t)row*K + k0 + q*4);
            bs[q*4+0][r] = v.x; bs[q*4+1][r] = v.y;
            bs[q*4+2][r] = v.z; bs[q*4+3][r] = v.w;
        }
        __syncthreads();
#pragma unroll
        for (int kk = 0; kk < 16; ++kk){
            float4 a0 = *(const float4*)&as[kk][tm*8];
            float4 a1 = *(const float4*)&as[kk][tm*8+4];
            float4 b0 = *(const float4*)&bs[kk][tn*4];
            float av[8] = {a0.x,a0.y,a0.z,a0.w,a1.x,a1.y,a1.z,a1.w};
            float bv[4] = {b0.x,b0.y,b0.z,b0.w};
#pragma unroll
            for (int i = 0; i < 8; ++i)
#pragma unroll
                for (int j = 0; j < 4; ++j) acc[i][j] += av[i]*bv[j];
        }
        __syncthreads();
    }
#pragma unroll
    for (int i = 0; i < 8; ++i){
        int m = m0 + tm*8 + i;
        if (GUARD && m >= M) continue;
#pragma unroll
        for (int j = 0; j < 4; ++j){
            int n = n0 + tn*4 + j;
            if (GUARD && n >= N) continue;
            float v = acc[i][j] + bias[n];
            size_t dst;
            if (REMAP){
                dst = ((size_t)(m & 31) * NSTEPS + (size_t)(m >> 5)) * VV + (size_t)n;
            } else {
                dst = (size_t)m * (size_t)N + (size_t)n;
            }
            Cm[dst] = v;
        }
    }
}

// ---------------------------------------------------------------------------
// per-wave 4b x 16rows gates GEMM, lanes split K; result left in cur[64]
// rows: r = (idx>>2)*1024 + d0 + (idx&3), idx = 0..15
template<int XSA, int NCA, int LDA, int XSB, int NCB, int LDB>
__device__ __forceinline__ void gates_16rows(
    const float* __restrict__ xa, const float* __restrict__ wa,
    const float* __restrict__ xb, const float* __restrict__ wb,
    int d0, int b0, int lane, float* cur)
{
#pragma unroll
    for (int k = 0; k < 64; ++k) cur[k] = 0.0f;
    size_t ra[16], rb[16];
#pragma unroll
    for (int idx = 0; idx < 16; ++idx){
        int r = (idx>>2)*1024 + d0 + (idx&3);
        ra[idx] = (size_t)r * LDA;
        rb[idx] = (size_t)r * LDB;
    }
    for (int kc = 0; kc < NCA; ++kc){
        int kb = kc*256 + lane*4;
        float4 xv[4];
#pragma unroll
        for (int i = 0; i < 4; ++i)
            xv[i] = *(const float4*)&xa[(size_t)(b0+i)*XSA + kb];
#pragma unroll
        for (int g2 = 0; g2 < 2; ++g2){
            float4 wv[8];
#pragma unroll
            for (int jj = 0; jj < 8; ++jj)
                wv[jj] = *(const float4*)&wa[ra[g2*8+jj] + kb];
#pragma unroll
            for (int i = 0; i < 4; ++i)
#pragma unroll
                for (int jj = 0; jj < 8; ++jj)
                    cur[i*16+g2*8+jj] += xv[i].x*wv[jj].x + xv[i].y*wv[jj].y
                                       + xv[i].z*wv[jj].z + xv[i].w*wv[jj].w;
        }
    }
    for (int kc = 0; kc < NCB; ++kc){
        int kb = kc*256 + lane*4;
        float4 xv[4];
#pragma unroll
        for (int i = 0; i < 4; ++i)
            xv[i] = *(const float4*)&xb[(size_t)(b0+i)*XSB + kb];
#pragma unroll
        for (int g2 = 0; g2 < 2; ++g2){
            float4 wv[8];
#pragma unroll
            for (int jj = 0; jj < 8; ++jj)
                wv[jj] = *(const float4*)&wb[rb[g2*8+jj] + kb];
#pragma unroll
            for (int i = 0; i < 4; ++i)
#pragma unroll
                for (int jj = 0; jj < 8; ++jj)
                    cur[i*16+g2*8+jj] += xv[i].x*wv[jj].x + xv[i].y*wv[jj].y
                                       + xv[i].z*wv[jj].z + xv[i].w*wv[jj].w;
        }
    }
}

// ---------------------------------------------------------------------------
__global__ __launch_bounds__(NTHR, 2) void k_persist(
    const float* __restrict__ hs, const int* __restrict__ hlens,
    const int* __restrict__ ys_pad, const float* __restrict__ embed_W,
    const float* __restrict__ w_ih0, const float* __restrict__ w_hh0,
    const float* __restrict__ b_ih0, const float* __restrict__ b_hh0,
    const float* __restrict__ w_ih1, const float* __restrict__ w_hh1,
    const float* __restrict__ b_ih1, const float* __restrict__ b_hh1,
    const float* __restrict__ dec_W, const float* __restrict__ conv_W,
    const float* __restrict__ att_W, const float* __restrict__ gvec_W,
    const float* __restrict__ gvec_b,
    const float* __restrict__ pre_enc, float* __restrict__ aw,
    float* __restrict__ e_buf, float* __restrict__ x0,
    float* __restrict__ z0a, float* __restrict__ z0b,
    float* __restrict__ z1a, float* __restrict__ z1b,
    float* __restrict__ g1dec, float* __restrict__ c0,
    float* __restrict__ c1, float* __restrict__ zs, int* __restrict__ bar)
{
    __shared__ float watt[AAD*12];       // per a: w0..9 | dec | gv
    __shared__ float cws[2016];          // conv weights [10][201]
    __shared__ float aws[264];
    __shared__ float convs[640];         // [c][64]
    __shared__ float ps[512];
    __shared__ float red[512];
    __shared__ float gs[32][17];
    __shared__ float decpart[512];       // [wave][64]
    __shared__ float bsum0[16], bsum1[16];

    const int blk  = blockIdx.x;
    const int tid  = threadIdx.x;
    const int w    = tid >> 6;
    const int lane = tid & 63;
    int* flags = bar;
    int* gen   = bar + 4096;

    const int b1 = blk >> 3;          // P1/P2 batch
    const int tc = blk & 7;           // P1 t-chunk
    const int t0 = tc * 64;
    const int ch = blk & 7;           // P2 E-chunk
    const int d0 = blk * 4;           // P3/P4 d-slice
    const int rd0 = blk * 2;          // P4 dec rows
    const int hl = hlens[b1];
    const float gb0 = gvec_b[0];

    // ---- one-time staging of constants ----
    for (int idx = tid; idx < AAD*10; idx += NTHR)
        watt[(idx/10)*12 + (idx%10)] = att_W[idx];
    for (int idx = tid; idx < AAD; idx += NTHR)
        watt[idx*12 + 11] = gvec_W[idx];
    for (int idx = tid; idx < 10*KW; idx += NTHR)
        cws[idx] = conv_W[idx];
    if (tid < 16){
        int r = (tid>>2)*1024 + d0 + (tid&3);
        bsum0[tid] = b_ih0[r] + b_hh0[r];
        bsum1[tid] = b_ih1[r] + b_hh1[r];
    }
    __syncthreads();

    int ep = 0;
    for (int s = 0; s < NSTEPS; ++s){
        float* z0in  = (s & 1) ? z0b : z0a;
        float* z0out = (s & 1) ? z0a : z0b;
        float* z1in  = (s & 1) ? z1b : z1a;
        float* z1out = (s & 1) ? z1a : z1b;

        // =========== P1: attention energy e[b1, t0..t0+64) ===========
        {
            // stage dec_proj (slot 10) + aw window
            watt[tid*12 + 10] = g1dec[b1*AAD + tid];           // tid == a (512)
            if (tid < 264){
                int t = t0 - NFILT + tid;
                aws[tid] = (t >= 0 && t < TT) ? aw[b1*TT + t] : 0.0f;
            }
            __syncthreads();
            // conv: [c][tl]
            for (int idx = tid; idx < 640; idx += NTHR){
                int c = idx >> 6, tl = idx & 63;
                const float* wc = &cws[c*KW];
                float sacc = 0.0f;
#pragma unroll 4
                for (int k = 0; k < KW; ++k) sacc += aws[tl + k] * wc[k];
                convs[c*64 + tl] = sacc;
            }
            __syncthreads();
            // energy: q=tid&7 interleave over a, tl=tid>>3
            const int q = tid & 7, tl = tid >> 3;
            const int t = t0 + tl;
            float cv[10];
#pragma unroll
            for (int c = 0; c < 10; ++c) cv[c] = convs[c*64 + tl];
            const float* pre_row = pre_enc + (size_t)(b1*TT + t)*AAD;
            float acc = 0.0f;
#pragma unroll 4
            for (int j = 0; j < 64; ++j){
                int a = (j << 3) | q;
                const float* wr = &watt[a*12];
                float4 w0 = *(const float4*)wr;
                float4 w1 = *(const float4*)(wr+4);
                float4 w2 = *(const float4*)(wr+8);   // w8, w9, dec, gv
                float cp = cv[0]*w0.x + cv[1]*w0.y + cv[2]*w0.z + cv[3]*w0.w
                         + cv[4]*w1.x + cv[5]*w1.y + cv[6]*w1.z + cv[7]*w1.w
                         + cv[8]*w2.x + cv[9]*w2.y;
                float v = pre_row[a] + w2.z + cp;
                acc += ftanh(v) * w2.w;
            }
            acc += __shfl_xor(acc, 1);
            acc += __shfl_xor(acc, 2);
            acc += __shfl_xor(acc, 4);
            if (q == 0) e_buf[b1*TT + t] = acc + gb0;
        }
        ep++; gbar(flags, gen, ep);

        // =========== P2: softmax + att_c + ey staging ===========
        {
            float ev = e_buf[b1*TT + tid];
            float v = (tid < hl) ? 2.0f*ev : -1e30f;
            float m = v;
#pragma unroll
            for (int ofs = 1; ofs < 64; ofs <<= 1) m = fmaxf(m, __shfl_xor(m, ofs));
            if (lane == 0) red[w] = m;
            __syncthreads();
            m = red[0];
#pragma unroll
            for (int k = 1; k < 8; ++k) m = fmaxf(m, red[k]);
            __syncthreads();
            float p = __expf(v - m);      // masked: exp(-huge) == 0
            float su = p;
#pragma unroll
            for (int ofs = 1; ofs < 64; ofs <<= 1) su += __shfl_xor(su, ofs);
            if (lane == 0) red[w] = su;
            __syncthreads();
            su = red[0];
#pragma unroll
            for (int k = 1; k < 8; ++k) su += red[k];
            float rinv = 1.0f / su;
            float pn = p * rinv;
            ps[tid] = pn;
            if (ch == 0) aw[b1*TT + tid] = pn;
            __syncthreads();
            // att_c over 128 cols, 4 t-quarters
            const int c = tid & 127, th = tid >> 7;
            const int col = ch*128 + c;
            const float* hcol = hs + (size_t)(b1*TT + th*128)*EE + col;
            float acc = 0.0f;
#pragma unroll 8
            for (int t2 = 0; t2 < 128; ++t2)
                acc += ps[th*128 + t2] * hcol[(size_t)t2*EE];
            red[tid] = acc;
            __syncthreads();
            if (th == 0){
                float attc = red[c] + red[c+128] + red[c+256] + red[c+384];
                x0[b1*2048 + 1024 + col] = attc;
                int tok = (s == 0) ? SOS : ys_pad[b1*128 + (s-1)];
                x0[b1*2048 + ch*128 + c] = embed_W[(size_t)tok*DD + ch*128 + c];
            }
        }
        ep++; gbar(flags, gen, ep);

        // =========== P3: gates0 + lstm0 ===========
        {
            const int b0 = w * 4;
            float cur[64];
            gates_16rows<2048,8,2048, 1024,4,1024>(x0, w_ih0, z0in, w_hh0,
                                                   d0, b0, lane, cur);
            butterfly64(cur, lane);
            int ci = (int)(__brev((unsigned)lane) >> 26);
            gs[b0 + (ci>>4)][ci & 15] = cur[0];
            __syncthreads();
            if (tid < 128){
                int b = tid >> 2, dl = tid & 3, d = d0 + dl;
                float gi = gs[b][dl]      + bsum0[dl];
                float gf = gs[b][4 + dl]  + bsum0[4 + dl];
                float gg = gs[b][8 + dl]  + bsum0[8 + dl];
                float go = gs[b][12 + dl] + bsum0[12 + dl];
                float c = fsig(gf)*c0[b*1024 + d] + fsig(gi)*ftanh(gg);
                float h = fsig(go)*ftanh(c);
                c0[b*1024 + d] = c;
                z0out[b*1024 + d] = h;
            }
        }
        ep++; gbar(flags, gen, ep);

        // =========== P4: gates1 + dec_proj + lstm1 ===========
        {
            const int b0 = w * 4;
            float cur[64];
            gates_16rows<1024,4,1024, 1024,4,1024>(z0out, w_ih1, z1in, w_hh1,
                                                   d0, b0, lane, cur);
            butterfly64(cur, lane);
            int ci = (int)(__brev((unsigned)lane) >> 26);
            gs[b0 + (ci>>4)][ci & 15] = cur[0];
            // dec_proj partial: wave w covers k-slice [w*128, w*128+128)
            {
                int ks = w*128 + lane*2;
                float2 dv0 = *(const float2*)&dec_W[(size_t)rd0*1024 + ks];
                float2 dv1 = *(const float2*)&dec_W[(size_t)(rd0+1)*1024 + ks];
                float cd[64];
#pragma unroll
                for (int b = 0; b < 32; ++b){
                    float2 zv = *(const float2*)&z0out[b*1024 + ks];
                    cd[b*2]   = zv.x*dv0.x + zv.y*dv0.y;
                    cd[b*2+1] = zv.x*dv1.x + zv.y*dv1.y;
                }
                butterfly64(cd, lane);
                int ci2 = (int)(__brev((unsigned)lane) >> 26);
                decpart[w*64 + ci2] = cd[0];
            }
            __syncthreads();
            if (tid < 128){
                int b = tid >> 2, dl = tid & 3, d = d0 + dl;
                float gi = gs[b][dl]      + bsum1[dl];
                float gf = gs[b][4 + dl]  + bsum1[4 + dl];
                float gg = gs[b][8 + dl]  + bsum1[8 + dl];
                float go = gs[b][12 + dl] + bsum1[12 + dl];
                float c = fsig(gf)*c1[b*1024 + d] + fsig(gi)*ftanh(gg);
                float h = fsig(go)*ftanh(c);
                c1[b*1024 + d] = c;
                z1out[b*1024 + d] = h;
                zs[(size_t)(s*32 + b)*1024 + d] = h;
            } else if (tid < 192){
                int o = tid - 128;
                float v = 0.0f;
#pragma unroll
                for (int wv = 0; wv < 8; ++wv) v += decpart[wv*64 + o];
                int b = o >> 1, rl = o & 1;
                g1dec[b*AAD + rd0 + rl] = v;
            }
        }
        ep++; gbar(flags, gen, ep);
    }
}

// ---------------------------------------------------------------------------
extern "C" void kernel_launch(void* const* d_in, const int* in_sizes, int n_in,
                              void* d_out, int out_size, void* d_ws, size_t ws_size,
                              hipStream_t stream)
{
    const float* hs      = (const float*)d_in[0];
    const int*   hlens   = (const int*)d_in[1];
    const int*   ys_pad  = (const int*)d_in[2];
    const float* embed_W = (const float*)d_in[3];
    const float* w_ih0   = (const float*)d_in[4];
    const float* w_hh0   = (const float*)d_in[5];
    const float* b_ih0   = (const float*)d_in[6];
    const float* b_hh0   = (const float*)d_in[7];
    const float* w_ih1   = (const float*)d_in[8];
    const float* w_hh1   = (const float*)d_in[9];
    const float* b_ih1   = (const float*)d_in[10];
    const float* b_hh1   = (const float*)d_in[11];
    const float* enc_W   = (const float*)d_in[12];
    const float* enc_b   = (const float*)d_in[13];
    const float* dec_W   = (const float*)d_in[14];
    const float* conv_W  = (const float*)d_in[15];
    const float* att_W   = (const float*)d_in[16];
    const float* gvec_W  = (const float*)d_in[17];
    const float* gvec_b  = (const float*)d_in[18];
    const float* out_W   = (const float*)d_in[19];
    const float* out_b   = (const float*)d_in[20];
    float* out = (float*)d_out;

    float* ws      = (float*)d_ws;
    float* pre_enc = ws;                    // [16384][512]
    float* aw      = pre_enc + 8388608;     // [32][512]
    float* e_buf   = aw + 16384;            // [32][512]
    float* x0      = e_buf + 16384;         // [32][2048]  ey | att_c
    float* z0a     = x0 + 65536;            // [32][1024]
    float* z0b     = z0a + 32768;
    float* z1a     = z0b + 32768;
    float* z1b     = z1a + 32768;
    float* g1dec   = z1b + 32768;           // [32][512]
    float* c0      = g1dec + 16384;         // [32][1024]
    float* c1      = c0 + 32768;            // [32][1024]
    float* zs      = c1 + 32768;            // [129][32][1024]
    int*   bar     = (int*)(zs + 4227072);  // flags[256*16] + gen

    k_init<<<128, 256, 0, stream>>>(hlens, aw, z0a, z1a, g1dec, c0, c1, bar);
    k_gemm_nt<false,false><<<dim3(128, 8), 256, 0, stream>>>(
        hs, enc_W, enc_b, pre_enc, 16384, 512, 1024);

    k_persist<<<NBLK, NTHR, 0, stream>>>(
        hs, hlens, ys_pad, embed_W,
        w_ih0, w_hh0, b_ih0, b_hh0,
        w_ih1, w_hh1, b_ih1, b_hh1,
        dec_W, conv_W, att_W, gvec_W, gvec_b,
        pre_enc, aw, e_buf, x0, z0a, z0b, z1a, z1b,
        g1dec, c0, c1, zs, bar);

    k_gemm_nt<true,true><<<dim3(33, 79), 256, 0, stream>>>(
        zs, out_W, out_b, out, 4128, 5000, 1024);
}

// Round 4
// 12561.284 us; speedup vs baseline: 1.7515x; 1.7515x over previous
//
#include <hip/hip_runtime.h>
#include <cstdint>
#include <cstddef>

#define BB 32
#define TT 512
#define NSTEPS 129   // L+1
#define EE 1024
#define DD 1024
#define AAD 512
#define VV 5000
#define SOS 4999
#define KW 201
#define NFILT 100
#define NBLK 256
#define NTHR 512

__device__ __forceinline__ float fsig(float x){
    return __fdividef(1.0f, 1.0f + __expf(-x));
}
__device__ __forceinline__ float ftanh(float x){
    float ax = fabsf(x);
    float e = __expf(-2.0f*ax);
    float r = __fdividef(1.0f - e, 1.0f + e);
    return copysignf(r, x);
}

// ---------------------------------------------------------------------------
// Coherence-point (MALL) access helpers: sc0 sc1 bypasses the non-coherent
// per-XCD L2s both ways. waitcnt folded into the same asm block so the
// output register is valid on asm exit (no rule-#18 scheduling hazard).
// Weights/hs/pre_enc keep NORMAL cached loads -> stay hot in L2/L3.
__device__ __forceinline__ float sc_load_f(const float* p){
    float v;
    asm volatile("global_load_dword %0, %1, off sc0 sc1\n\t"
                 "s_waitcnt vmcnt(0)"
                 : "=&v"(v) : "v"(p) : "memory");
    return v;
}
__device__ __forceinline__ void sc_store_f(float* p, float v){
    asm volatile("global_store_dword %0, %1, off sc0 sc1"
                 :: "v"(p), "v"(v) : "memory");
}
__device__ __forceinline__ int sc_load_i(const int* p){
    int v;
    asm volatile("global_load_dword %0, %1, off sc0 sc1\n\t"
                 "s_waitcnt vmcnt(0)"
                 : "=&v"(v) : "v"(p) : "memory");
    return v;
}
__device__ __forceinline__ void sc_store_i(int* p, int v){
    asm volatile("global_store_dword %0, %1, off sc0 sc1"
                 :: "v"(p), "v"(v) : "memory");
}
// 4 independent float4 coherent loads + single drain (batched MLP).
__device__ __forceinline__ void sc_gather4(const float* p0, const float* p1,
                                           const float* p2, const float* p3,
                                           float4& v0, float4& v1,
                                           float4& v2, float4& v3){
    asm volatile(
        "global_load_dwordx4 %0, %4, off sc0 sc1\n\t"
        "global_load_dwordx4 %1, %5, off sc0 sc1\n\t"
        "global_load_dwordx4 %2, %6, off sc0 sc1\n\t"
        "global_load_dwordx4 %3, %7, off sc0 sc1\n\t"
        "s_waitcnt vmcnt(0)"
        : "=&v"(v0), "=&v"(v1), "=&v"(v2), "=&v"(v3)
        : "v"(p0), "v"(p1), "v"(p2), "v"(p3) : "memory");
}

// 64-lane reduce-scatter butterfly: on exit lane l holds component bitrev6(l)
__device__ __forceinline__ void butterfly64(float* cur, int lane){
#pragma unroll
    for (int rb = 0; rb < 6; ++rb){
        const int bit = 1 << rb;
        const int half = 32 >> rb;
        const bool up = (lane & bit) != 0;
#pragma unroll
        for (int i = 0; i < half; ++i){
            float lo = cur[i], hi = cur[i + half];
            float send = up ? lo : hi;
            float keep = up ? hi : lo;
            cur[i] = keep + __shfl_xor(send, bit);
        }
    }
}

// grid barrier: per-wave vmcnt drain (all sc stores globally visible) ->
// flag store (sc) -> master aggregates -> gen bump. NO cache maintenance ops.
__device__ __forceinline__ void gbar(int* flags, int* gen, int ep){
    asm volatile("s_waitcnt vmcnt(0)" ::: "memory");
    __syncthreads();
    if (blockIdx.x == 0){
        if (threadIdx.x == 0) sc_store_i(&flags[0], ep);
        if (threadIdx.x < NBLK){
            while (sc_load_i(&flags[threadIdx.x*16]) < ep)
                __builtin_amdgcn_s_sleep(4);
        }
        __syncthreads();
        if (threadIdx.x == 0){
            asm volatile("s_waitcnt vmcnt(0)" ::: "memory");
            sc_store_i(gen, ep);
        }
    } else {
        if (threadIdx.x == 0){
            sc_store_i(&flags[blockIdx.x*16], ep);
            while (sc_load_i(gen) < ep)
                __builtin_amdgcn_s_sleep(4);
        }
    }
    __syncthreads();
}

// ---------------------------------------------------------------------------
__global__ void k_init(const int* __restrict__ hlens, float* __restrict__ aw,
                       float* __restrict__ z0a, float* __restrict__ z1a,
                       float* __restrict__ g1dec, float* __restrict__ c0,
                       float* __restrict__ c1, int* __restrict__ bar)
{
    int idx = blockIdx.x*256 + threadIdx.x;   // 128 blocks -> 32768 threads
    if (idx < BB*TT){
        int b = idx >> 9, t = idx & 511;
        int hl = hlens[b];
        aw[idx] = (t < hl) ? __fdividef(1.0f, (float)hl) : 0.0f;
    }
    if (idx < BB*1024){
        z0a[idx] = 0.0f; z1a[idx] = 0.0f; c0[idx] = 0.0f; c1[idx] = 0.0f;
    }
    if (idx < BB*AAD) g1dec[idx] = 0.0f;
    if (idx < 8192)   bar[idx] = 0;
}

// ---------------------------------------------------------------------------
// generic fp32 NT GEMM (verified R2): C[m][n]=sum_k A[m][k]B[n][k]+bias
template<bool GUARD, bool REMAP>
__global__ __launch_bounds__(256) void k_gemm_nt(
    const float* __restrict__ Am, const float* __restrict__ Bm,
    const float* __restrict__ bias, float* __restrict__ Cm,
    int M, int N, int K)
{
    __shared__ float as[16][132];
    __shared__ float bs[16][68];
    const int tid = threadIdx.x;
    const int m0 = blockIdx.x * 128, n0 = blockIdx.y * 64;
    const int tm = tid & 15, tn = tid >> 4;
    float acc[8][4];
#pragma unroll
    for (int i = 0; i < 8; ++i)
#pragma unroll
        for (int j = 0; j < 4; ++j) acc[i][j] = 0.0f;

    for (int k0 = 0; k0 < K; k0 += 16){
#pragma unroll
        for (int i = 0; i < 2; ++i){
            int idx = tid + i*256;
            int r = idx >> 2, q = idx & 3;
            int row = m0 + r;
            float4 v = make_float4(0.f,0.f,0.f,0.f);
            if (!GUARD || row < M) v = *(const float4*)(Am + (size_t)row*K + k0 + q*4);
            as[q*4+0][r] = v.x; as[q*4+1][r] = v.y;
            as[q*4+2][r] = v.z; as[q*4+3][r] = v.w;
        }
        {
            int r = tid >> 2, q = tid & 3;
            int row = n0 + r;
            float4 v = make_float4(0.f,0.f,0.f,0.f);
            if (!GUARD || row < N) v = *(const float4*)(Bm + (size_t)row*K + k0 + q*4);
            bs[q*4+0][r] = v.x; bs[q*4+1][r] = v.y;
            bs[q*4+2][r] = v.z; bs[q*4+3][r] = v.w;
        }
        __syncthreads();
#pragma unroll
        for (int kk = 0; kk < 16; ++kk){
            float4 a0 = *(const float4*)&as[kk][tm*8];
            float4 a1 = *(const float4*)&as[kk][tm*8+4];
            float4 b0 = *(const float4*)&bs[kk][tn*4];
            float av[8] = {a0.x,a0.y,a0.z,a0.w,a1.x,a1.y,a1.z,a1.w};
            float bv[4] = {b0.x,b0.y,b0.z,b0.w};
#pragma unroll
            for (int i = 0; i < 8; ++i)
#pragma unroll
                for (int j = 0; j < 4; ++j) acc[i][j] += av[i]*bv[j];
        }
        __syncthreads();
    }
#pragma unroll
    for (int i = 0; i < 8; ++i){
        int m = m0 + tm*8 + i;
        if (GUARD && m >= M) continue;
#pragma unroll
        for (int j = 0; j < 4; ++j){
            int n = n0 + tn*4 + j;
            if (GUARD && n >= N) continue;
            float v = acc[i][j] + bias[n];
            size_t dst;
            if (REMAP){
                dst = ((size_t)(m & 31) * NSTEPS + (size_t)(m >> 5)) * VV + (size_t)n;
            } else {
                dst = (size_t)m * (size_t)N + (size_t)n;
            }
            Cm[dst] = v;
        }
    }
}

// ---------------------------------------------------------------------------
// per-wave 4b x 16rows gates GEMM; x operands via coherent gathers, weights
// via normal cached loads. DEC=1 additionally accumulates 2 dec_W rows
// (rd0, rd0+1) against the A-operand into curd[8] (4 batches x 2 rows).
template<int XS_A, int NC_A, int LD_A, int XS_B, int NC_B, int LD_B, int DEC>
__device__ __forceinline__ void gates_16rows(
    const float* __restrict__ xa, const float* __restrict__ wa,
    const float* __restrict__ xb, const float* __restrict__ wb,
    const float* __restrict__ dwv, int rd0,
    int d0, int b0, int lane, float* cur, float* curd)
{
#pragma unroll
    for (int k = 0; k < 64; ++k) cur[k] = 0.0f;
    if (DEC){
#pragma unroll
        for (int k = 0; k < 8; ++k) curd[k] = 0.0f;
    }
    size_t ra[16], rb[16];
#pragma unroll
    for (int idx = 0; idx < 16; ++idx){
        int r = (idx>>2)*1024 + d0 + (idx&3);
        ra[idx] = (size_t)r * LD_A;
        rb[idx] = (size_t)r * LD_B;
    }
    for (int kc = 0; kc < NC_A; ++kc){
        int kb = kc*256 + lane*4;
        float4 xv[4];
        sc_gather4(&xa[(size_t)(b0+0)*XS_A + kb], &xa[(size_t)(b0+1)*XS_A + kb],
                   &xa[(size_t)(b0+2)*XS_A + kb], &xa[(size_t)(b0+3)*XS_A + kb],
                   xv[0], xv[1], xv[2], xv[3]);
#pragma unroll
        for (int g2 = 0; g2 < 2; ++g2){
            float4 wv[8];
#pragma unroll
            for (int jj = 0; jj < 8; ++jj)
                wv[jj] = *(const float4*)&wa[ra[g2*8+jj] + kb];
#pragma unroll
            for (int i = 0; i < 4; ++i)
#pragma unroll
                for (int jj = 0; jj < 8; ++jj)
                    cur[i*16+g2*8+jj] += xv[i].x*wv[jj].x + xv[i].y*wv[jj].y
                                       + xv[i].z*wv[jj].z + xv[i].w*wv[jj].w;
        }
        if (DEC){
            float4 dv0 = *(const float4*)&dwv[(size_t)rd0*1024 + kb];
            float4 dv1 = *(const float4*)&dwv[(size_t)(rd0+1)*1024 + kb];
#pragma unroll
            for (int i = 0; i < 4; ++i){
                curd[i*2]   += xv[i].x*dv0.x + xv[i].y*dv0.y
                             + xv[i].z*dv0.z + xv[i].w*dv0.w;
                curd[i*2+1] += xv[i].x*dv1.x + xv[i].y*dv1.y
                             + xv[i].z*dv1.z + xv[i].w*dv1.w;
            }
        }
    }
    for (int kc = 0; kc < NC_B; ++kc){
        int kb = kc*256 + lane*4;
        float4 xv[4];
        sc_gather4(&xb[(size_t)(b0+0)*XS_B + kb], &xb[(size_t)(b0+1)*XS_B + kb],
                   &xb[(size_t)(b0+2)*XS_B + kb], &xb[(size_t)(b0+3)*XS_B + kb],
                   xv[0], xv[1], xv[2], xv[3]);
#pragma unroll
        for (int g2 = 0; g2 < 2; ++g2){
            float4 wv[8];
#pragma unroll
            for (int jj = 0; jj < 8; ++jj)
                wv[jj] = *(const float4*)&wb[rb[g2*8+jj] + kb];
#pragma unroll
            for (int i = 0; i < 4; ++i)
#pragma unroll
                for (int jj = 0; jj < 8; ++jj)
                    cur[i*16+g2*8+jj] += xv[i].x*wv[jj].x + xv[i].y*wv[jj].y
                                       + xv[i].z*wv[jj].z + xv[i].w*wv[jj].w;
        }
    }
}

// ---------------------------------------------------------------------------
__global__ __launch_bounds__(NTHR, 2) void k_persist(
    const float* __restrict__ hs, const int* __restrict__ hlens,
    const int* __restrict__ ys_pad, const float* __restrict__ embed_W,
    const float* __restrict__ w_ih0, const float* __restrict__ w_hh0,
    const float* __restrict__ b_ih0, const float* __restrict__ b_hh0,
    const float* __restrict__ w_ih1, const float* __restrict__ w_hh1,
    const float* __restrict__ b_ih1, const float* __restrict__ b_hh1,
    const float* __restrict__ dec_W, const float* __restrict__ conv_W,
    const float* __restrict__ att_W, const float* __restrict__ gvec_W,
    const float* __restrict__ gvec_b,
    const float* __restrict__ pre_enc, float* __restrict__ aw,
    float* __restrict__ e_buf, float* __restrict__ x0,
    float* __restrict__ z0a, float* __restrict__ z0b,
    float* __restrict__ z1a, float* __restrict__ z1b,
    float* __restrict__ g1dec, float* __restrict__ c0,
    float* __restrict__ c1, float* __restrict__ zs, int* __restrict__ bar)
{
    __shared__ float watt[AAD*12];       // per a: w0..9 | dec | gv
    __shared__ float cws[2016];          // conv weights [10][201]
    __shared__ float aws[264];
    __shared__ float convs[640];         // [c][64]
    __shared__ float ps[512];
    __shared__ float red[512];
    __shared__ float gs[32][17];
    __shared__ float bsum0[16], bsum1[16];

    const int blk  = blockIdx.x;
    const int tid  = threadIdx.x;
    const int w    = tid >> 6;
    const int lane = tid & 63;
    int* flags = bar;
    int* gen   = bar + 4096;

    const int b1 = blk >> 3;          // P1/P2 batch
    const int tc = blk & 7;           // P1 t-chunk
    const int t0 = tc * 64;
    const int ch = blk & 7;           // P2 E-chunk
    const int d0 = blk * 4;           // P3/P4 d-slice
    const int rd0 = blk * 2;          // P4 dec rows
    const int hl = hlens[b1];
    const float gb0 = gvec_b[0];

    // ---- one-time staging of constants (normal cached loads) ----
    for (int idx = tid; idx < AAD*10; idx += NTHR)
        watt[(idx/10)*12 + (idx%10)] = att_W[idx];
    for (int idx = tid; idx < AAD; idx += NTHR)
        watt[idx*12 + 11] = gvec_W[idx];
    for (int idx = tid; idx < 10*KW; idx += NTHR)
        cws[idx] = conv_W[idx];
    if (tid < 16){
        int r = (tid>>2)*1024 + d0 + (tid&3);
        bsum0[tid] = b_ih0[r] + b_hh0[r];
        bsum1[tid] = b_ih1[r] + b_hh1[r];
    }
    __syncthreads();

    int ep = 0;
    for (int s = 0; s < NSTEPS; ++s){
        float* z0in  = (s & 1) ? z0b : z0a;
        float* z0out = (s & 1) ? z0a : z0b;
        float* z1in  = (s & 1) ? z1b : z1a;
        float* z1out = (s & 1) ? z1a : z1b;

        // =========== P1: attention energy e[b1, t0..t0+64) ===========
        {
            watt[tid*12 + 10] = sc_load_f(&g1dec[b1*AAD + tid]);  // tid == a
            if (tid < 264){
                int t = t0 - NFILT + tid;
                aws[tid] = (t >= 0 && t < TT) ? sc_load_f(&aw[b1*TT + t]) : 0.0f;
            }
            __syncthreads();
            for (int idx = tid; idx < 640; idx += NTHR){
                int c = idx >> 6, tl = idx & 63;
                const float* wc = &cws[c*KW];
                float sacc = 0.0f;
#pragma unroll 4
                for (int k = 0; k < KW; ++k) sacc += aws[tl + k] * wc[k];
                convs[c*64 + tl] = sacc;
            }
            __syncthreads();
            const int q = tid & 7, tl = tid >> 3;
            const int t = t0 + tl;
            float cv[10];
#pragma unroll
            for (int c = 0; c < 10; ++c) cv[c] = convs[c*64 + tl];
            const float* pre_row = pre_enc + (size_t)(b1*TT + t)*AAD;
            float acc = 0.0f;
#pragma unroll 4
            for (int j = 0; j < 64; ++j){
                int a = (j << 3) | q;
                const float* wr = &watt[a*12];
                float4 w0 = *(const float4*)wr;
                float4 w1 = *(const float4*)(wr+4);
                float4 w2 = *(const float4*)(wr+8);   // w8, w9, dec, gv
                float cp = cv[0]*w0.x + cv[1]*w0.y + cv[2]*w0.z + cv[3]*w0.w
                         + cv[4]*w1.x + cv[5]*w1.y + cv[6]*w1.z + cv[7]*w1.w
                         + cv[8]*w2.x + cv[9]*w2.y;
                float v = pre_row[a] + w2.z + cp;
                acc += ftanh(v) * w2.w;
            }
            acc += __shfl_xor(acc, 1);
            acc += __shfl_xor(acc, 2);
            acc += __shfl_xor(acc, 4);
            if (q == 0) sc_store_f(&e_buf[b1*TT + t], acc + gb0);
        }
        ep++; gbar(flags, gen, ep);

        // =========== P2: softmax + att_c + ey staging ===========
        {
            float ev = sc_load_f(&e_buf[b1*TT + tid]);
            float v = (tid < hl) ? 2.0f*ev : -1e30f;
            float m = v;
#pragma unroll
            for (int ofs = 1; ofs < 64; ofs <<= 1) m = fmaxf(m, __shfl_xor(m, ofs));
            if (lane == 0) red[w] = m;
            __syncthreads();
            m = red[0];
#pragma unroll
            for (int k = 1; k < 8; ++k) m = fmaxf(m, red[k]);
            __syncthreads();
            float p = __expf(v - m);
            float su = p;
#pragma unroll
            for (int ofs = 1; ofs < 64; ofs <<= 1) su += __shfl_xor(su, ofs);
            if (lane == 0) red[w] = su;
            __syncthreads();
            su = red[0];
#pragma unroll
            for (int k = 1; k < 8; ++k) su += red[k];
            float rinv = 1.0f / su;
            float pn = p * rinv;
            ps[tid] = pn;
            if (ch == 0) sc_store_f(&aw[b1*TT + tid], pn);
            __syncthreads();
            const int c = tid & 127, th = tid >> 7;
            const int col = ch*128 + c;
            const float* hcol = hs + (size_t)(b1*TT + th*128)*EE + col;
            float acc = 0.0f;
#pragma unroll 8
            for (int t2 = 0; t2 < 128; ++t2)
                acc += ps[th*128 + t2] * hcol[(size_t)t2*EE];
            red[tid] = acc;
            __syncthreads();
            if (th == 0){
                float attc = red[c] + red[c+128] + red[c+256] + red[c+384];
                sc_store_f(&x0[b1*2048 + 1024 + col], attc);
                int tok = (s == 0) ? SOS : ys_pad[b1*128 + (s-1)];
                sc_store_f(&x0[b1*2048 + ch*128 + c],
                           embed_W[(size_t)tok*DD + ch*128 + c]);
            }
        }
        ep++; gbar(flags, gen, ep);

        // =========== P3: gates0 + lstm0 ===========
        {
            const int b0 = w * 4;
            float cur[64], curd_unused[8];
            gates_16rows<2048,8,2048, 1024,4,1024, 0>(
                x0, w_ih0, z0in, w_hh0, nullptr, 0, d0, b0, lane, cur, curd_unused);
            butterfly64(cur, lane);
            int ci = (int)(__brev((unsigned)lane) >> 26);
            gs[b0 + (ci>>4)][ci & 15] = cur[0];
            __syncthreads();
            if (tid < 128){
                int b = tid >> 2, dl = tid & 3, d = d0 + dl;
                float gi = gs[b][dl]      + bsum0[dl];
                float gf = gs[b][4 + dl]  + bsum0[4 + dl];
                float gg = gs[b][8 + dl]  + bsum0[8 + dl];
                float go = gs[b][12 + dl] + bsum0[12 + dl];
                float c = fsig(gf)*c0[b*1024 + d] + fsig(gi)*ftanh(gg);
                float h = fsig(go)*ftanh(c);
                c0[b*1024 + d] = c;                     // private: normal store
                sc_store_f(&z0out[b*1024 + d], h);      // cross-block
            }
        }
        ep++; gbar(flags, gen, ep);

        // =========== P4: gates1 + fused dec_proj + lstm1 ===========
        {
            const int b0 = w * 4;
            float cur[64], curd[8];
            gates_16rows<1024,4,1024, 1024,4,1024, 1>(
                z0out, w_ih1, z1in, w_hh1, dec_W, rd0, d0, b0, lane, cur, curd);
            butterfly64(cur, lane);
            int ci = (int)(__brev((unsigned)lane) >> 26);
            gs[b0 + (ci>>4)][ci & 15] = cur[0];
            // dec reduce: 3 scatter stages + 3 allreduce stages
#pragma unroll
            for (int rb = 0; rb < 3; ++rb){
                const int bit = 1 << rb;
                const int half = 4 >> rb;
                const bool up = (lane & bit) != 0;
#pragma unroll
                for (int i = 0; i < half; ++i){
                    float lo = curd[i], hi = curd[i + half];
                    float send = up ? lo : hi;
                    float keep = up ? hi : lo;
                    curd[i] = keep + __shfl_xor(send, bit);
                }
            }
            float dv = curd[0];
            dv += __shfl_xor(dv, 8);
            dv += __shfl_xor(dv, 16);
            dv += __shfl_xor(dv, 32);
            if (lane < 8){
                int ci2 = ((lane&1)<<2) | (lane&2) | ((lane>>2)&1);  // bitrev3
                sc_store_f(&g1dec[(b0 + (ci2>>1))*AAD + rd0 + (ci2&1)], dv);
            }
            __syncthreads();
            if (tid < 128){
                int b = tid >> 2, dl = tid & 3, d = d0 + dl;
                float gi = gs[b][dl]      + bsum1[dl];
                float gf = gs[b][4 + dl]  + bsum1[4 + dl];
                float gg = gs[b][8 + dl]  + bsum1[8 + dl];
                float go = gs[b][12 + dl] + bsum1[12 + dl];
                float c = fsig(gf)*c1[b*1024 + d] + fsig(gi)*ftanh(gg);
                float h = fsig(go)*ftanh(c);
                c1[b*1024 + d] = c;                     // private: normal store
                sc_store_f(&z1out[b*1024 + d], h);      // cross-block
                zs[(size_t)(s*32 + b)*1024 + d] = h;    // read after kernel end
            }
        }
        ep++; gbar(flags, gen, ep);
    }
}

// ---------------------------------------------------------------------------
extern "C" void kernel_launch(void* const* d_in, const int* in_sizes, int n_in,
                              void* d_out, int out_size, void* d_ws, size_t ws_size,
                              hipStream_t stream)
{
    const float* hs      = (const float*)d_in[0];
    const int*   hlens   = (const int*)d_in[1];
    const int*   ys_pad  = (const int*)d_in[2];
    const float* embed_W = (const float*)d_in[3];
    const float* w_ih0   = (const float*)d_in[4];
    const float* w_hh0   = (const float*)d_in[5];
    const float* b_ih0   = (const float*)d_in[6];
    const float* b_hh0   = (const float*)d_in[7];
    const float* w_ih1   = (const float*)d_in[8];
    const float* w_hh1   = (const float*)d_in[9];
    const float* b_ih1   = (const float*)d_in[10];
    const float* b_hh1   = (const float*)d_in[11];
    const float* enc_W   = (const float*)d_in[12];
    const float* enc_b   = (const float*)d_in[13];
    const float* dec_W   = (const float*)d_in[14];
    const float* conv_W  = (const float*)d_in[15];
    const float* att_W   = (const float*)d_in[16];
    const float* gvec_W  = (const float*)d_in[17];
    const float* gvec_b  = (const float*)d_in[18];
    const float* out_W   = (const float*)d_in[19];
    const float* out_b   = (const float*)d_in[20];
    float* out = (float*)d_out;

    float* ws      = (float*)d_ws;
    float* pre_enc = ws;                    // [16384][512]
    float* aw      = pre_enc + 8388608;     // [32][512]
    float* e_buf   = aw + 16384;            // [32][512]
    float* x0      = e_buf + 16384;         // [32][2048]  ey | att_c
    float* z0a     = x0 + 65536;            // [32][1024]
    float* z0b     = z0a + 32768;
    float* z1a     = z0b + 32768;
    float* z1b     = z1a + 32768;
    float* g1dec   = z1b + 32768;           // [32][512]
    float* c0      = g1dec + 16384;         // [32][1024]
    float* c1      = c0 + 32768;            // [32][1024]
    float* zs      = c1 + 32768;            // [129][32][1024]
    int*   bar     = (int*)(zs + 4227072);  // flags[256*16] + gen

    k_init<<<128, 256, 0, stream>>>(hlens, aw, z0a, z1a, g1dec, c0, c1, bar);
    k_gemm_nt<false,false><<<dim3(128, 8), 256, 0, stream>>>(
        hs, enc_W, enc_b, pre_enc, 16384, 512, 1024);

    k_persist<<<NBLK, NTHR, 0, stream>>>(
        hs, hlens, ys_pad, embed_W,
        w_ih0, w_hh0, b_ih0, b_hh0,
        w_ih1, w_hh1, b_ih1, b_hh1,
        dec_W, conv_W, att_W, gvec_W, gvec_b,
        pre_enc, aw, e_buf, x0, z0a, z0b, z1a, z1b,
        g1dec, c0, c1, zs, bar);

    k_gemm_nt<true,true><<<dim3(33, 79), 256, 0, stream>>>(
        zs, out_W, out_b, out, 4128, 5000, 1024);
}